// Round 3
// baseline (233.808 us; speedup 1.0000x reference)
//
#include <hip/hip_runtime.h>
#include <hip/hip_bf16.h>
#include <hip/hip_fp16.h>

// EnhancedProxyNCALoss: B=4096, C=10000, D=128, SCALE=10, alpha=.25, gamma=2,
// k = int(9999*0.3) = 2999.
// Pipeline: prep (normalize+bf16 into ws, zero out) ->
//           bf16 MFMA gemm writing sim as 16-bit monotonic half-keys ->
//           per-row single-PASS 2048-bin select + focal epilogue.
// R3: select is now ONE pass over the keys. Histogram pass also accumulates
//     per-bin value sums (ds_add_f32) for positive keys (key>=0x8000 <=> bin
//     >=1024). Denominator computed from bins: sum_{bin>b} cnt*exp(mean-10)
//     + fill*exp(mean_b-10). Jensen error ~4e-5 rel << bf16 gemm noise.
//     Exact re-read fallback kept for the (unseen) b<1024 case.

#define BATCH   4096
#define NCLASS  10000
#define EDIM    128
#define KSEL    2999
#define LDK     136
#define MLOG    10.0f   // sim <= 10 always (cosine * SCALE) -> safe softmax max

typedef __attribute__((ext_vector_type(8))) short short8;
typedef __attribute__((ext_vector_type(4))) float floatx4;

__device__ __forceinline__ unsigned short f2bf(float f) {
    unsigned int u = __float_as_uint(f);
    unsigned int r = (u + 0x7FFFu + ((u >> 16) & 1u)) >> 16;   // RNE
    return (unsigned short)r;
}
// float -> half (RNE) -> monotonic 16-bit key (order-preserving)
__device__ __forceinline__ unsigned int f2key16(float x) {
    unsigned short hb = __half_as_ushort(__float2half(x));
    return (hb & 0x8000u) ? (unsigned int)(~hb & 0xFFFFu)
                          : (unsigned int)(hb | 0x8000u);
}
__device__ __forceinline__ float key16val(unsigned int k) {
    unsigned short hb = (k & 0x8000u) ? (unsigned short)(k ^ 0x8000u)
                                      : (unsigned short)(~k & 0xFFFFu);
    return __half2float(__ushort_as_half(hb));
}

// ---------------------------------------------------------------- prep ------
__global__ __launch_bounds__(256) void prep_kernel(
    const float* __restrict__ emb, const float* __restrict__ px,
    unsigned short* __restrict__ px_bf, unsigned short* __restrict__ emb_bf,
    float* __restrict__ out)
{
    const int tid  = threadIdx.x;
    if (blockIdx.x == 0 && tid == 0) out[0] = 0.0f;
    const int lane = tid & 63;
    const int w    = tid >> 6;
    const int row  = blockIdx.x * 4 + w;   // grid = 3524 -> rows 0..14095

    const float* src;
    unsigned short* dst;
    float scale;
    if (row < NCLASS) {
        src = px + (size_t)row * EDIM;  dst = px_bf + (size_t)row * EDIM;  scale = 1.0f;
    } else {
        int r = row - NCLASS;
        src = emb + (size_t)r * EDIM;   dst = emb_bf + (size_t)r * EDIM;   scale = 10.0f;
    }
    float a = src[lane], b = src[lane + 64];
    float ss = a * a + b * b;
    #pragma unroll
    for (int off = 32; off; off >>= 1) ss += __shfl_xor(ss, off);
    float inv = scale / fmaxf(sqrtf(ss), 1e-12f);
    dst[lane]      = f2bf(a * inv);
    dst[lane + 64] = f2bf(b * inv);
}

// ---------------------------------------------------------------- gemm ------
// sim = emb10_hat . px_hat^T, bf16 MFMA 16x16x32, fp32 acc, 128x128 tile.
// Epilogue: fp32 -> half -> monotonic key16, LDS transpose (reuse Als),
// coalesced uint4 stores (8 keys / 16 B per lane).
__global__ __launch_bounds__(256) void gemm_kernel(
    const unsigned short* __restrict__ emb_bf,
    const unsigned short* __restrict__ px_bf,
    unsigned short* __restrict__ simk, int row0)
{
    __shared__ __align__(16) unsigned short Als[128 * LDK];
    __shared__ __align__(16) unsigned short Bls[128 * LDK];

    const int tid  = threadIdx.x;
    const int lane = tid & 63;
    const int w    = tid >> 6;
    const int c0   = blockIdx.x * 128;
    const int rg0  = row0 + blockIdx.y * 128;

    #pragma unroll
    for (int i = 0; i < 8; ++i) {
        int c  = tid + i * 256;
        int r  = c >> 4;
        int kc = (c & 15) << 3;
        uint4 v = *(const uint4*)(emb_bf + (size_t)(rg0 + r) * EDIM + kc);
        *(uint4*)(Als + r * LDK + kc) = v;
    }
    #pragma unroll
    for (int i = 0; i < 8; ++i) {
        int c  = tid + i * 256;
        int n  = c >> 4;
        int kc = (c & 15) << 3;
        uint4 v = make_uint4(0u, 0u, 0u, 0u);
        if (c0 + n < NCLASS)
            v = *(const uint4*)(px_bf + (size_t)(c0 + n) * EDIM + kc);
        *(uint4*)(Bls + n * LDK + kc) = v;
    }
    __syncthreads();

    const int wr = (w >> 1) * 64;
    const int wc = (w & 1) * 64;
    const int fm = lane & 15;
    const int fq = lane >> 4;

    floatx4 acc[4][4];
    #pragma unroll
    for (int i = 0; i < 4; ++i)
        #pragma unroll
        for (int j = 0; j < 4; ++j)
            acc[i][j] = (floatx4){0.f, 0.f, 0.f, 0.f};

    #pragma unroll
    for (int kk = 0; kk < 4; ++kk) {
        const int kof = kk * 32 + fq * 8;
        short8 a[4], b[4];
        #pragma unroll
        for (int i = 0; i < 4; ++i)
            a[i] = *(const short8*)(Als + (wr + i * 16 + fm) * LDK + kof);
        #pragma unroll
        for (int j = 0; j < 4; ++j)
            b[j] = *(const short8*)(Bls + (wc + j * 16 + fm) * LDK + kof);
        #pragma unroll
        for (int i = 0; i < 4; ++i)
            #pragma unroll
            for (int j = 0; j < 4; ++j)
                acc[i][j] = __builtin_amdgcn_mfma_f32_16x16x32_bf16(
                    a[i], b[j], acc[i][j], 0, 0, 0);
    }

    __syncthreads();                       // all LDS reads done; reuse Als
    unsigned short* T = Als;               // 128 x LDK key16 tile
    // C/D layout: col = lane&15, row = (lane>>4)*4 + reg
    #pragma unroll
    for (int j = 0; j < 4; ++j) {
        int col = wc + j * 16 + fm;
        #pragma unroll
        for (int i = 0; i < 4; ++i) {
            int rbase = wr + i * 16 + fq * 4;
            #pragma unroll
            for (int r = 0; r < 4; ++r)
                T[(rbase + r) * LDK + col] = (unsigned short)f2key16(acc[i][j][r]);
        }
    }
    __syncthreads();

    const int rl0 = blockIdx.y * 128;
    #pragma unroll
    for (int t = 0; t < 8; ++t) {
        int idx = t * 256 + tid;
        int rowl = idx >> 4;
        int g    = idx & 15;
        int col  = c0 + g * 8;
        if (col < NCLASS) {                // 10000 % 8 == 0 -> group all-valid
            uint4 v = *(const uint4*)(T + rowl * LDK + g * 8);
            *(uint4*)(simk + (size_t)(rl0 + rowl) * NCLASS + col) = v;
        }
    }
}

// -------------------------------------------------------------- select ------
// One block per batch row, SINGLE pass over the 10000 keys:
//   hist[bin]  += 1          (all keys)
//   sumv[bin]  += value      (positive keys only; positive <=> bin >= 1024)
// Register suffix-scan finds boundary bin b (KSEL-th largest). If b >= 1024
// (always true for this data: threshold ~ +0.46), denominator is computed
// per-bin: cnt*exp(mean-MLOG) for bins > b, fill*exp(mean_b-MLOG) at b.
// Exact fallback (re-read keys from global, L3-hot) if b < 1024.
__global__ __launch_bounds__(256, 8) void select_kernel(
    const unsigned short* __restrict__ simk, const int* __restrict__ labels,
    const float* __restrict__ cw, float* __restrict__ out, int row0)
{
    __shared__ __align__(16) unsigned int hist[2048];     // 8 KB
    __shared__ __align__(16) float        sumv[2048];     // 8 KB
    __shared__ __align__(16) unsigned int psum[256];      // 1 KB
    __shared__ float fred[8];
    __shared__ float s_pos;
    __shared__ unsigned int s_b, s_fill, s_cntb;

    const int tid   = threadIdx.x;
    const int lane  = tid & 63;
    const int w     = tid >> 6;
    const int rl    = blockIdx.x;
    const int label = labels[row0 + rl];
    const unsigned short* srow = simk + (size_t)rl * NCLASS;

    // prefetch positive key early (consumed after hist barrier)
    unsigned short poskey = 0;
    if (tid == 0) poskey = srow[label];

    {
        uint4 z = make_uint4(0u, 0u, 0u, 0u);
        *(uint4*)&hist[tid * 8]     = z;
        *(uint4*)&hist[tid * 8 + 4] = z;
        float4 zf = make_float4(0.f, 0.f, 0.f, 0.f);
        *(float4*)&sumv[tid * 8]     = zf;
        *(float4*)&sumv[tid * 8 + 4] = zf;
    }

    // issue all row loads up front (latency overlap), then single fused pass
    uint4 kv[5];
    kv[4] = make_uint4(0u, 0u, 0u, 0u);
    #pragma unroll
    for (int t = 0; t < 5; ++t) {
        int i = tid + t * 256;                       // 1250 groups total
        if (i < NCLASS / 8) kv[t] = *(const uint4*)(srow + i * 8);
    }
    __syncthreads();                                 // zeroed LDS visible

    #pragma unroll
    for (int t = 0; t < 5; ++t) {
        int i = tid + t * 256;
        if (i < NCLASS / 8) {
            unsigned int p[4] = {kv[t].x, kv[t].y, kv[t].z, kv[t].w};
            #pragma unroll
            for (int q = 0; q < 4; ++q) {
                unsigned int klo = p[q] & 0xFFFFu;
                unsigned int khi = p[q] >> 16;
                atomicAdd(&hist[klo >> 5], 1u);
                atomicAdd(&hist[khi >> 5], 1u);
                if (klo & 0x8000u)   // positive half <=> bin >= 1024
                    atomicAdd(&sumv[klo >> 5],
                        __half2float(__ushort_as_half((unsigned short)(klo ^ 0x8000u))));
                if (khi & 0x8000u)
                    atomicAdd(&sumv[khi >> 5],
                        __half2float(__ushort_as_half((unsigned short)(khi ^ 0x8000u))));
            }
        }
    }
    __syncthreads();
    if (tid == 0) {
        s_pos = key16val(poskey);
        hist[poskey >> 5] -= 1u;          // exclude positive from selection
        if (poskey & 0x8000u) sumv[poskey >> 5] -= s_pos;
    }
    __syncthreads();

    // ---- suffix scan over 2048 bins; only sfx[8] kept live ----
    uint4 h0 = *(const uint4*)&hist[tid * 8];
    uint4 h1 = *(const uint4*)&hist[tid * 8 + 4];
    unsigned int sfx[8];
    sfx[7] = h1.w;
    sfx[6] = sfx[7] + h1.z;
    sfx[5] = sfx[6] + h1.y;
    sfx[4] = sfx[5] + h1.x;
    sfx[3] = sfx[4] + h0.w;
    sfx[2] = sfx[3] + h0.z;
    sfx[1] = sfx[2] + h0.y;
    sfx[0] = sfx[1] + h0.x;
    psum[tid] = sfx[0];
    __syncthreads();
    if (w == 0) {
        uint4 g = *(const uint4*)&psum[lane * 4];
        unsigned int gs = g.x + g.y + g.z + g.w;
        unsigned int s = gs;
        #pragma unroll
        for (int off = 1; off < 64; off <<= 1) {
            unsigned int o = __shfl_down(s, off);
            if (lane + off < 64) s += o;
        }
        unsigned int above = s - gs;       // partials in strictly-higher lanes
        unsigned int a3 = above;
        unsigned int a2 = a3 + g.w;
        unsigned int a1 = a2 + g.z;
        unsigned int a0 = a1 + g.y;
        psum[lane * 4 + 0] = a0; psum[lane * 4 + 1] = a1;
        psum[lane * 4 + 2] = a2; psum[lane * 4 + 3] = a3;
    }
    __syncthreads();
    {
        unsigned int add = psum[tid];      // keys in bins of threads > tid
        #pragma unroll
        for (int i = 0; i < 8; ++i) {
            unsigned int cur = sfx[i] + add;
            unsigned int nxt = ((i < 7) ? sfx[i + 1] : 0u) + add;
            if (cur >= KSEL && nxt < KSEL) {   // exactly one (tid,i) matches
                s_b    = (unsigned int)(tid * 8 + i);
                s_fill = KSEL - nxt;
                s_cntb = sfx[i] - ((i < 7) ? sfx[i + 1] : 0u);
            }
        }
    }
    __syncthreads();

    // ---- denominator ----
    const unsigned int b = s_b;
    float sum = 0.f, bsum = 0.f;           // bsum used by exact fallback only
    if (b >= 1024u) {
        // fast path: per-bin mean exp; all bins >= b hold positive keys only
        const float fillf = (float)s_fill;
        float4 sv0 = *(const float4*)&sumv[tid * 8];
        float4 sv1 = *(const float4*)&sumv[tid * 8 + 4];
        float sv[8] = {sv0.x, sv0.y, sv0.z, sv0.w, sv1.x, sv1.y, sv1.z, sv1.w};
        #pragma unroll
        for (int i = 0; i < 8; ++i) {
            unsigned int bin = (unsigned int)(tid * 8 + i);
            unsigned int c = sfx[i] - ((i < 7) ? sfx[i + 1] : 0u);
            if (bin >= b && c) {
                float m = sv[i] / (float)c;
                float e = __expf(m - MLOG);
                sum += ((bin > b) ? (float)c : fillf) * e;
            }
        }
    } else {
        // exact fallback: re-read keys (L3-hot), old two-class exp sum
        for (int i = tid; i < NCLASS / 8; i += 256) {
            uint4 pk = *(const uint4*)(srow + i * 8);
            unsigned int p[4] = {pk.x, pk.y, pk.z, pk.w};
            #pragma unroll
            for (int q = 0; q < 4; ++q) {
                unsigned int klo = p[q] & 0xFFFFu;
                unsigned int khi = p[q] >> 16;
                unsigned int blo = klo >> 5, bhi = khi >> 5;
                int idx = i * 8 + q * 2;
                if (blo >= b && idx != label) {
                    float e = __expf(key16val(klo) - MLOG);
                    if (blo > b) sum += e; else bsum += e;
                }
                if (bhi >= b && (idx + 1) != label) {
                    float e = __expf(key16val(khi) - MLOG);
                    if (bhi > b) sum += e; else bsum += e;
                }
            }
        }
    }
    #pragma unroll
    for (int off = 32; off; off >>= 1) {
        sum  += __shfl_xor(sum, off);
        bsum += __shfl_xor(bsum, off);
    }
    if (lane == 0) { fred[w] = sum; fred[4 + w] = bsum; }
    __syncthreads();

    if (tid == 0) {
        float S  = fred[0] + fred[1] + fred[2] + fred[3];
        float Bs = fred[4] + fred[5] + fred[6] + fred[7];   // 0 on fast path
        float ep = __expf(s_pos - MLOG);
        float denom = S + Bs * ((float)s_fill / (float)s_cntb) + ep;
        float p  = ep / denom;
        float ce = -logf(p + 1e-8f);
        float focal = 0.25f * (1.0f - p) * (1.0f - p) * ce;
        atomicAdd(out, focal * cw[label] * (1.0f / (float)BATCH));
    }
}

// ------------------------------------------------------------ launcher ------
extern "C" void kernel_launch(void* const* d_in, const int* in_sizes, int n_in,
                              void* d_out, int out_size, void* d_ws, size_t ws_size,
                              hipStream_t stream) {
    const float* emb    = (const float*)d_in[0];   // 4096 x 128
    const int*   labels = (const int*)d_in[1];     // 4096
    const float* cw     = (const float*)d_in[2];   // 10000
    const float* px     = (const float*)d_in[3];   // 10000 x 128
    float* out = (float*)d_out;
    char*  wsc = (char*)d_ws;

    unsigned short* px_bf  = (unsigned short*)wsc;               // 10000*128 bf16
    unsigned short* emb_bf = (unsigned short*)(wsc + 2560000);   // 4096*128 bf16
    unsigned short* simk   = (unsigned short*)(wsc + 3608576);   // chunk x 10000 key16

    size_t fixed = 3608576;
    size_t avail = (ws_size > fixed) ? (ws_size - fixed) : 0;
    long long cap = (long long)(avail / ((size_t)NCLASS * 2));
    int chunk = (int)((cap / 128) * 128);
    if (chunk > BATCH) chunk = BATCH;
    if (chunk < 128) chunk = 128;

    prep_kernel<<<3524, 256, 0, stream>>>(emb, px, px_bf, emb_bf, out);

    for (int r0 = 0; r0 < BATCH; r0 += chunk) {
        int rows = (BATCH - r0 < chunk) ? (BATCH - r0) : chunk;
        dim3 ggrid((NCLASS + 127) / 128, rows / 128);
        gemm_kernel<<<ggrid, 256, 0, stream>>>(emb_bf, px_bf, simk, r0);
        select_kernel<<<rows, 256, 0, stream>>>(simk, labels, cw, out, r0);
    }
}

// Round 4
// 168.632 us; speedup vs baseline: 1.3865x; 1.3865x over previous
//
#include <hip/hip_runtime.h>
#include <hip/hip_bf16.h>
#include <hip/hip_fp16.h>

// EnhancedProxyNCALoss: B=4096, C=10000, D=128, SCALE=10, alpha=.25, gamma=2,
// k = int(9999*0.3) = 2999.
// Pipeline: prep (normalize+bf16 into ws, zero out) ->
//           bf16 MFMA gemm writing sim as 16-bit monotonic half-keys ->
//           per-row single-PASS packed-histogram select + focal epilogue.
// R4: R3's per-bin-mean algorithm, but accumulation is ONE native u32 LDS
//     atomic per key: word = (count<<20) | sum(key&31). (R3's float LDS
//     atomicAdd lowered to a CAS retry loop -> 2x regression, VALUBusy 8.7%.)
//     Within a bin (32 aligned half-ULPs) value is affine in key bits, so
//     bin mean value = v0 + (rbar/32)*(v32-v0) exactly. No carry: r-sum <=
//     31*10000 < 2^20; count field overflow would need >=4096 keys in one
//     ~3%-wide bin (impossible for this data; b<1024 exact fallback kept).

#define BATCH   4096
#define NCLASS  10000
#define EDIM    128
#define KSEL    2999
#define LDK     136
#define MLOG    10.0f   // sim <= 10 always (cosine * SCALE) -> safe softmax max

typedef __attribute__((ext_vector_type(8))) short short8;
typedef __attribute__((ext_vector_type(4))) float floatx4;

__device__ __forceinline__ unsigned short f2bf(float f) {
    unsigned int u = __float_as_uint(f);
    unsigned int r = (u + 0x7FFFu + ((u >> 16) & 1u)) >> 16;   // RNE
    return (unsigned short)r;
}
// float -> half (RNE) -> monotonic 16-bit key (order-preserving)
__device__ __forceinline__ unsigned int f2key16(float x) {
    unsigned short hb = __half_as_ushort(__float2half(x));
    return (hb & 0x8000u) ? (unsigned int)(~hb & 0xFFFFu)
                          : (unsigned int)(hb | 0x8000u);
}
__device__ __forceinline__ float key16val(unsigned int k) {
    unsigned short hb = (k & 0x8000u) ? (unsigned short)(k ^ 0x8000u)
                                      : (unsigned short)(~k & 0xFFFFu);
    return __half2float(__ushort_as_half(hb));
}

// ---------------------------------------------------------------- prep ------
__global__ __launch_bounds__(256) void prep_kernel(
    const float* __restrict__ emb, const float* __restrict__ px,
    unsigned short* __restrict__ px_bf, unsigned short* __restrict__ emb_bf,
    float* __restrict__ out)
{
    const int tid  = threadIdx.x;
    if (blockIdx.x == 0 && tid == 0) out[0] = 0.0f;
    const int lane = tid & 63;
    const int w    = tid >> 6;
    const int row  = blockIdx.x * 4 + w;   // grid = 3524 -> rows 0..14095

    const float* src;
    unsigned short* dst;
    float scale;
    if (row < NCLASS) {
        src = px + (size_t)row * EDIM;  dst = px_bf + (size_t)row * EDIM;  scale = 1.0f;
    } else {
        int r = row - NCLASS;
        src = emb + (size_t)r * EDIM;   dst = emb_bf + (size_t)r * EDIM;   scale = 10.0f;
    }
    float a = src[lane], b = src[lane + 64];
    float ss = a * a + b * b;
    #pragma unroll
    for (int off = 32; off; off >>= 1) ss += __shfl_xor(ss, off);
    float inv = scale / fmaxf(sqrtf(ss), 1e-12f);
    dst[lane]      = f2bf(a * inv);
    dst[lane + 64] = f2bf(b * inv);
}

// ---------------------------------------------------------------- gemm ------
// sim = emb10_hat . px_hat^T, bf16 MFMA 16x16x32, fp32 acc, 128x128 tile.
// Epilogue: fp32 -> half -> monotonic key16, LDS transpose (reuse Als),
// coalesced uint4 stores (8 keys / 16 B per lane).
__global__ __launch_bounds__(256) void gemm_kernel(
    const unsigned short* __restrict__ emb_bf,
    const unsigned short* __restrict__ px_bf,
    unsigned short* __restrict__ simk, int row0)
{
    __shared__ __align__(16) unsigned short Als[128 * LDK];
    __shared__ __align__(16) unsigned short Bls[128 * LDK];

    const int tid  = threadIdx.x;
    const int lane = tid & 63;
    const int w    = tid >> 6;
    const int c0   = blockIdx.x * 128;
    const int rg0  = row0 + blockIdx.y * 128;

    #pragma unroll
    for (int i = 0; i < 8; ++i) {
        int c  = tid + i * 256;
        int r  = c >> 4;
        int kc = (c & 15) << 3;
        uint4 v = *(const uint4*)(emb_bf + (size_t)(rg0 + r) * EDIM + kc);
        *(uint4*)(Als + r * LDK + kc) = v;
    }
    #pragma unroll
    for (int i = 0; i < 8; ++i) {
        int c  = tid + i * 256;
        int n  = c >> 4;
        int kc = (c & 15) << 3;
        uint4 v = make_uint4(0u, 0u, 0u, 0u);
        if (c0 + n < NCLASS)
            v = *(const uint4*)(px_bf + (size_t)(c0 + n) * EDIM + kc);
        *(uint4*)(Bls + n * LDK + kc) = v;
    }
    __syncthreads();

    const int wr = (w >> 1) * 64;
    const int wc = (w & 1) * 64;
    const int fm = lane & 15;
    const int fq = lane >> 4;

    floatx4 acc[4][4];
    #pragma unroll
    for (int i = 0; i < 4; ++i)
        #pragma unroll
        for (int j = 0; j < 4; ++j)
            acc[i][j] = (floatx4){0.f, 0.f, 0.f, 0.f};

    #pragma unroll
    for (int kk = 0; kk < 4; ++kk) {
        const int kof = kk * 32 + fq * 8;
        short8 a[4], b[4];
        #pragma unroll
        for (int i = 0; i < 4; ++i)
            a[i] = *(const short8*)(Als + (wr + i * 16 + fm) * LDK + kof);
        #pragma unroll
        for (int j = 0; j < 4; ++j)
            b[j] = *(const short8*)(Bls + (wc + j * 16 + fm) * LDK + kof);
        #pragma unroll
        for (int i = 0; i < 4; ++i)
            #pragma unroll
            for (int j = 0; j < 4; ++j)
                acc[i][j] = __builtin_amdgcn_mfma_f32_16x16x32_bf16(
                    a[i], b[j], acc[i][j], 0, 0, 0);
    }

    __syncthreads();                       // all LDS reads done; reuse Als
    unsigned short* T = Als;               // 128 x LDK key16 tile
    // C/D layout: col = lane&15, row = (lane>>4)*4 + reg
    #pragma unroll
    for (int j = 0; j < 4; ++j) {
        int col = wc + j * 16 + fm;
        #pragma unroll
        for (int i = 0; i < 4; ++i) {
            int rbase = wr + i * 16 + fq * 4;
            #pragma unroll
            for (int r = 0; r < 4; ++r)
                T[(rbase + r) * LDK + col] = (unsigned short)f2key16(acc[i][j][r]);
        }
    }
    __syncthreads();

    const int rl0 = blockIdx.y * 128;
    #pragma unroll
    for (int t = 0; t < 8; ++t) {
        int idx = t * 256 + tid;
        int rowl = idx >> 4;
        int g    = idx & 15;
        int col  = c0 + g * 8;
        if (col < NCLASS) {                // 10000 % 8 == 0 -> group all-valid
            uint4 v = *(const uint4*)(T + rowl * LDK + g * 8);
            *(uint4*)(simk + (size_t)(rl0 + rowl) * NCLASS + col) = v;
        }
    }
}

// -------------------------------------------------------------- select ------
// One block per batch row, SINGLE pass over the 10000 keys. Packed histogram:
//   hist[bin] += (1<<20) | (key & 31)     (one ds_add_u32 per key)
// count = hist>>20, r-sum = hist & 0xFFFFF. Register suffix-scan on counts
// finds boundary bin b (KSEL-th largest). Fast path (b >= 1024, i.e. positive
// threshold -- always true here): denominator from bins,
//   sum_{bin>b} cnt*exp(vmean-MLOG) + fill*exp(vmean_b-MLOG),
// vmean = v0 + (rbar/32)*(v32-v0)  (exact: value affine in key bits per bin).
// Exact fallback (re-read keys from global, L3-hot) if b < 1024.
__global__ __launch_bounds__(256, 8) void select_kernel(
    const unsigned short* __restrict__ simk, const int* __restrict__ labels,
    const float* __restrict__ cw, float* __restrict__ out, int row0)
{
    __shared__ __align__(16) unsigned int hist[2048];     // 8 KB (packed)
    __shared__ __align__(16) unsigned int psum[256];      // 1 KB
    __shared__ float fred[8];
    __shared__ float s_pos;
    __shared__ unsigned int s_b, s_fill, s_cntb;

    const int tid   = threadIdx.x;
    const int lane  = tid & 63;
    const int w     = tid >> 6;
    const int rl    = blockIdx.x;
    const int label = labels[row0 + rl];
    const unsigned short* srow = simk + (size_t)rl * NCLASS;

    // prefetch positive key early (consumed after hist barrier)
    unsigned short poskey = 0;
    if (tid == 0) poskey = srow[label];

    {
        uint4 z = make_uint4(0u, 0u, 0u, 0u);
        *(uint4*)&hist[tid * 8]     = z;
        *(uint4*)&hist[tid * 8 + 4] = z;
    }

    // issue all row loads up front (latency overlap), then single fused pass
    uint4 kv[5];
    kv[4] = make_uint4(0u, 0u, 0u, 0u);
    #pragma unroll
    for (int t = 0; t < 5; ++t) {
        int i = tid + t * 256;                       // 1250 groups total
        if (i < NCLASS / 8) kv[t] = *(const uint4*)(srow + i * 8);
    }
    __syncthreads();                                 // zeroed LDS visible

    // packed histogram: branchless, one u32 atomic per key
    #pragma unroll
    for (int t = 0; t < 5; ++t) {
        int i = tid + t * 256;
        if (i < NCLASS / 8) {
            unsigned int p[4] = {kv[t].x, kv[t].y, kv[t].z, kv[t].w};
            #pragma unroll
            for (int q = 0; q < 4; ++q) {
                unsigned int klo = p[q] & 0xFFFFu;
                unsigned int khi = p[q] >> 16;
                atomicAdd(&hist[klo >> 5], 0x100000u | (klo & 31u));
                atomicAdd(&hist[khi >> 5], 0x100000u | (khi & 31u));
            }
        }
    }
    __syncthreads();
    if (tid == 0) {
        s_pos = key16val(poskey);
        // exclude positive: dec count and its r contribution
        hist[poskey >> 5] -= 0x100000u | ((unsigned int)poskey & 31u);
    }
    __syncthreads();

    // ---- suffix scan over 2048 bins (counts); packed words kept live ----
    uint4 h0 = *(const uint4*)&hist[tid * 8];
    uint4 h1 = *(const uint4*)&hist[tid * 8 + 4];
    unsigned int wd[8] = {h0.x, h0.y, h0.z, h0.w, h1.x, h1.y, h1.z, h1.w};
    unsigned int sfx[8];
    sfx[7] = wd[7] >> 20;
    #pragma unroll
    for (int i = 6; i >= 0; --i) sfx[i] = sfx[i + 1] + (wd[i] >> 20);
    psum[tid] = sfx[0];
    __syncthreads();
    if (w == 0) {
        uint4 g = *(const uint4*)&psum[lane * 4];
        unsigned int gs = g.x + g.y + g.z + g.w;
        unsigned int s = gs;
        #pragma unroll
        for (int off = 1; off < 64; off <<= 1) {
            unsigned int o = __shfl_down(s, off);
            if (lane + off < 64) s += o;
        }
        unsigned int above = s - gs;       // partials in strictly-higher lanes
        unsigned int a3 = above;
        unsigned int a2 = a3 + g.w;
        unsigned int a1 = a2 + g.z;
        unsigned int a0 = a1 + g.y;
        psum[lane * 4 + 0] = a0; psum[lane * 4 + 1] = a1;
        psum[lane * 4 + 2] = a2; psum[lane * 4 + 3] = a3;
    }
    __syncthreads();
    {
        unsigned int add = psum[tid];      // keys in bins of threads > tid
        #pragma unroll
        for (int i = 0; i < 8; ++i) {
            unsigned int cur = sfx[i] + add;
            unsigned int nxt = ((i < 7) ? sfx[i + 1] : 0u) + add;
            if (cur >= KSEL && nxt < KSEL) {   // exactly one (tid,i) matches
                s_b    = (unsigned int)(tid * 8 + i);
                s_fill = KSEL - nxt;
                s_cntb = sfx[i] - ((i < 7) ? sfx[i + 1] : 0u);
            }
        }
    }
    __syncthreads();

    // ---- denominator ----
    const unsigned int b = s_b;
    float sum = 0.f, bsum = 0.f;           // bsum used by exact fallback only
    if (b >= 1024u) {
        // fast path: per-bin mean exp from packed words
        const float fillf = (float)s_fill;
        #pragma unroll
        for (int i = 0; i < 8; ++i) {
            unsigned int bin = (unsigned int)(tid * 8 + i);
            unsigned int c = wd[i] >> 20;
            if (bin >= b && c) {
                float rbar = (float)(wd[i] & 0xFFFFFu) / (float)c;
                unsigned int kb = bin << 5;
                float v0  = key16val(kb);
                float v32 = key16val(kb + 32u);
                float vm  = v0 + (v32 - v0) * (rbar * 0.03125f);
                float e = __expf(vm - MLOG);
                sum += ((bin > b) ? (float)c : fillf) * e;
            }
        }
    } else {
        // exact fallback: re-read keys (L3-hot), old two-class exp sum
        for (int i = tid; i < NCLASS / 8; i += 256) {
            uint4 pk = *(const uint4*)(srow + i * 8);
            unsigned int p[4] = {pk.x, pk.y, pk.z, pk.w};
            #pragma unroll
            for (int q = 0; q < 4; ++q) {
                unsigned int klo = p[q] & 0xFFFFu;
                unsigned int khi = p[q] >> 16;
                unsigned int blo = klo >> 5, bhi = khi >> 5;
                int idx = i * 8 + q * 2;
                if (blo >= b && idx != label) {
                    float e = __expf(key16val(klo) - MLOG);
                    if (blo > b) sum += e; else bsum += e;
                }
                if (bhi >= b && (idx + 1) != label) {
                    float e = __expf(key16val(khi) - MLOG);
                    if (bhi > b) sum += e; else bsum += e;
                }
            }
        }
    }
    #pragma unroll
    for (int off = 32; off; off >>= 1) {
        sum  += __shfl_xor(sum, off);
        bsum += __shfl_xor(bsum, off);
    }
    if (lane == 0) { fred[w] = sum; fred[4 + w] = bsum; }
    __syncthreads();

    if (tid == 0) {
        float S  = fred[0] + fred[1] + fred[2] + fred[3];
        float Bs = fred[4] + fred[5] + fred[6] + fred[7];   // 0 on fast path
        float ep = __expf(s_pos - MLOG);
        float denom = S + Bs * ((float)s_fill / (float)s_cntb) + ep;
        float p  = ep / denom;
        float ce = -logf(p + 1e-8f);
        float focal = 0.25f * (1.0f - p) * (1.0f - p) * ce;
        atomicAdd(out, focal * cw[label] * (1.0f / (float)BATCH));
    }
}

// ------------------------------------------------------------ launcher ------
extern "C" void kernel_launch(void* const* d_in, const int* in_sizes, int n_in,
                              void* d_out, int out_size, void* d_ws, size_t ws_size,
                              hipStream_t stream) {
    const float* emb    = (const float*)d_in[0];   // 4096 x 128
    const int*   labels = (const int*)d_in[1];     // 4096
    const float* cw     = (const float*)d_in[2];   // 10000
    const float* px     = (const float*)d_in[3];   // 10000 x 128
    float* out = (float*)d_out;
    char*  wsc = (char*)d_ws;

    unsigned short* px_bf  = (unsigned short*)wsc;               // 10000*128 bf16
    unsigned short* emb_bf = (unsigned short*)(wsc + 2560000);   // 4096*128 bf16
    unsigned short* simk   = (unsigned short*)(wsc + 3608576);   // chunk x 10000 key16

    size_t fixed = 3608576;
    size_t avail = (ws_size > fixed) ? (ws_size - fixed) : 0;
    long long cap = (long long)(avail / ((size_t)NCLASS * 2));
    int chunk = (int)((cap / 128) * 128);
    if (chunk > BATCH) chunk = BATCH;
    if (chunk < 128) chunk = 128;

    prep_kernel<<<3524, 256, 0, stream>>>(emb, px, px_bf, emb_bf, out);

    for (int r0 = 0; r0 < BATCH; r0 += chunk) {
        int rows = (BATCH - r0 < chunk) ? (BATCH - r0) : chunk;
        dim3 ggrid((NCLASS + 127) / 128, rows / 128);
        gemm_kernel<<<ggrid, 256, 0, stream>>>(emb_bf, px_bf, simk, r0);
        select_kernel<<<rows, 256, 0, stream>>>(simk, labels, cw, out, r0);
    }
}

// Round 5
// 130.654 us; speedup vs baseline: 1.7895x; 1.2907x over previous
//
#include <hip/hip_runtime.h>
#include <hip/hip_bf16.h>
#include <hip/hip_fp16.h>

// EnhancedProxyNCALoss: B=4096, C=10000, D=128, SCALE=10, alpha=.25, gamma=2,
// k = int(9999*0.3) = 2999.
// Pipeline: prep (normalize+bf16 into ws) ->
//           bf16 MFMA gemm writing sim as 16-bit monotonic half-keys ->
//           per-row single-pass packed-histogram select -> 1-block reduce.
// R5: kill the single-address global atomicAdd tail. Evidence: select dur
//     pinned at 63-73us across wildly different internal structures (R0-R4);
//     WRITE_SIZE = 2048 x 64B = one HBM line per block-atomic. 2048 blocks x
//     same-4-byte device-scope RMW serialize at the memory-side coherence
//     point (~60us). Now: plain store to partials[row], tiny reduce kernel.

#define BATCH   4096
#define NCLASS  10000
#define EDIM    128
#define KSEL    2999
#define LDK     136
#define MLOG    10.0f   // sim <= 10 always (cosine * SCALE) -> safe softmax max

typedef __attribute__((ext_vector_type(8))) short short8;
typedef __attribute__((ext_vector_type(4))) float floatx4;

__device__ __forceinline__ unsigned short f2bf(float f) {
    unsigned int u = __float_as_uint(f);
    unsigned int r = (u + 0x7FFFu + ((u >> 16) & 1u)) >> 16;   // RNE
    return (unsigned short)r;
}
// float -> half (RNE) -> monotonic 16-bit key (order-preserving)
__device__ __forceinline__ unsigned int f2key16(float x) {
    unsigned short hb = __half_as_ushort(__float2half(x));
    return (hb & 0x8000u) ? (unsigned int)(~hb & 0xFFFFu)
                          : (unsigned int)(hb | 0x8000u);
}
__device__ __forceinline__ float key16val(unsigned int k) {
    unsigned short hb = (k & 0x8000u) ? (unsigned short)(k ^ 0x8000u)
                                      : (unsigned short)(~k & 0xFFFFu);
    return __half2float(__ushort_as_half(hb));
}

// ---------------------------------------------------------------- prep ------
__global__ __launch_bounds__(256) void prep_kernel(
    const float* __restrict__ emb, const float* __restrict__ px,
    unsigned short* __restrict__ px_bf, unsigned short* __restrict__ emb_bf)
{
    const int tid  = threadIdx.x;
    const int lane = tid & 63;
    const int w    = tid >> 6;
    const int row  = blockIdx.x * 4 + w;   // grid = 3524 -> rows 0..14095

    const float* src;
    unsigned short* dst;
    float scale;
    if (row < NCLASS) {
        src = px + (size_t)row * EDIM;  dst = px_bf + (size_t)row * EDIM;  scale = 1.0f;
    } else {
        int r = row - NCLASS;
        src = emb + (size_t)r * EDIM;   dst = emb_bf + (size_t)r * EDIM;   scale = 10.0f;
    }
    float a = src[lane], b = src[lane + 64];
    float ss = a * a + b * b;
    #pragma unroll
    for (int off = 32; off; off >>= 1) ss += __shfl_xor(ss, off);
    float inv = scale / fmaxf(sqrtf(ss), 1e-12f);
    dst[lane]      = f2bf(a * inv);
    dst[lane + 64] = f2bf(b * inv);
}

// ---------------------------------------------------------------- gemm ------
// sim = emb10_hat . px_hat^T, bf16 MFMA 16x16x32, fp32 acc, 128x128 tile.
// Epilogue: fp32 -> half -> monotonic key16, LDS transpose (reuse Als),
// coalesced uint4 stores (8 keys / 16 B per lane).
__global__ __launch_bounds__(256) void gemm_kernel(
    const unsigned short* __restrict__ emb_bf,
    const unsigned short* __restrict__ px_bf,
    unsigned short* __restrict__ simk, int row0)
{
    __shared__ __align__(16) unsigned short Als[128 * LDK];
    __shared__ __align__(16) unsigned short Bls[128 * LDK];

    const int tid  = threadIdx.x;
    const int lane = tid & 63;
    const int w    = tid >> 6;
    const int c0   = blockIdx.x * 128;
    const int rg0  = row0 + blockIdx.y * 128;

    #pragma unroll
    for (int i = 0; i < 8; ++i) {
        int c  = tid + i * 256;
        int r  = c >> 4;
        int kc = (c & 15) << 3;
        uint4 v = *(const uint4*)(emb_bf + (size_t)(rg0 + r) * EDIM + kc);
        *(uint4*)(Als + r * LDK + kc) = v;
    }
    #pragma unroll
    for (int i = 0; i < 8; ++i) {
        int c  = tid + i * 256;
        int n  = c >> 4;
        int kc = (c & 15) << 3;
        uint4 v = make_uint4(0u, 0u, 0u, 0u);
        if (c0 + n < NCLASS)
            v = *(const uint4*)(px_bf + (size_t)(c0 + n) * EDIM + kc);
        *(uint4*)(Bls + n * LDK + kc) = v;
    }
    __syncthreads();

    const int wr = (w >> 1) * 64;
    const int wc = (w & 1) * 64;
    const int fm = lane & 15;
    const int fq = lane >> 4;

    floatx4 acc[4][4];
    #pragma unroll
    for (int i = 0; i < 4; ++i)
        #pragma unroll
        for (int j = 0; j < 4; ++j)
            acc[i][j] = (floatx4){0.f, 0.f, 0.f, 0.f};

    #pragma unroll
    for (int kk = 0; kk < 4; ++kk) {
        const int kof = kk * 32 + fq * 8;
        short8 a[4], b[4];
        #pragma unroll
        for (int i = 0; i < 4; ++i)
            a[i] = *(const short8*)(Als + (wr + i * 16 + fm) * LDK + kof);
        #pragma unroll
        for (int j = 0; j < 4; ++j)
            b[j] = *(const short8*)(Bls + (wc + j * 16 + fm) * LDK + kof);
        #pragma unroll
        for (int i = 0; i < 4; ++i)
            #pragma unroll
            for (int j = 0; j < 4; ++j)
                acc[i][j] = __builtin_amdgcn_mfma_f32_16x16x32_bf16(
                    a[i], b[j], acc[i][j], 0, 0, 0);
    }

    __syncthreads();                       // all LDS reads done; reuse Als
    unsigned short* T = Als;               // 128 x LDK key16 tile
    // C/D layout: col = lane&15, row = (lane>>4)*4 + reg
    #pragma unroll
    for (int j = 0; j < 4; ++j) {
        int col = wc + j * 16 + fm;
        #pragma unroll
        for (int i = 0; i < 4; ++i) {
            int rbase = wr + i * 16 + fq * 4;
            #pragma unroll
            for (int r = 0; r < 4; ++r)
                T[(rbase + r) * LDK + col] = (unsigned short)f2key16(acc[i][j][r]);
        }
    }
    __syncthreads();

    const int rl0 = blockIdx.y * 128;
    #pragma unroll
    for (int t = 0; t < 8; ++t) {
        int idx = t * 256 + tid;
        int rowl = idx >> 4;
        int g    = idx & 15;
        int col  = c0 + g * 8;
        if (col < NCLASS) {                // 10000 % 8 == 0 -> group all-valid
            uint4 v = *(const uint4*)(T + rowl * LDK + g * 8);
            *(uint4*)(simk + (size_t)(rl0 + rowl) * NCLASS + col) = v;
        }
    }
}

// -------------------------------------------------------------- select ------
// One block per batch row, SINGLE pass over the 10000 keys. Packed histogram:
//   hist[bin] += (1<<20) | (key & 31)     (one ds_add_u32 per key)
// count = hist>>20, r-sum = hist & 0xFFFFF. Register suffix-scan on counts
// finds boundary bin b (KSEL-th largest). Fast path (b >= 1024, i.e. positive
// threshold -- always true here): denominator from bins,
//   sum_{bin>b} cnt*exp(vmean-MLOG) + fill*exp(vmean_b-MLOG),
// vmean = v0 + (rbar/32)*(v32-v0)  (exact: value affine in key bits per bin).
// Exact fallback (re-read keys from global, L3-hot) if b < 1024.
// Result: PLAIN STORE to partials[row] (no global atomic).
__global__ __launch_bounds__(256, 8) void select_kernel(
    const unsigned short* __restrict__ simk, const int* __restrict__ labels,
    const float* __restrict__ cw, float* __restrict__ partials, int row0)
{
    __shared__ __align__(16) unsigned int hist[2048];     // 8 KB (packed)
    __shared__ __align__(16) unsigned int psum[256];      // 1 KB
    __shared__ float fred[8];
    __shared__ float s_pos;
    __shared__ unsigned int s_b, s_fill, s_cntb;

    const int tid   = threadIdx.x;
    const int lane  = tid & 63;
    const int w     = tid >> 6;
    const int rl    = blockIdx.x;
    const int label = labels[row0 + rl];
    const unsigned short* srow = simk + (size_t)rl * NCLASS;

    // prefetch positive key early (consumed after hist barrier)
    unsigned short poskey = 0;
    if (tid == 0) poskey = srow[label];

    {
        uint4 z = make_uint4(0u, 0u, 0u, 0u);
        *(uint4*)&hist[tid * 8]     = z;
        *(uint4*)&hist[tid * 8 + 4] = z;
    }

    // issue all row loads up front (latency overlap), then single fused pass
    uint4 kv[5];
    kv[4] = make_uint4(0u, 0u, 0u, 0u);
    #pragma unroll
    for (int t = 0; t < 5; ++t) {
        int i = tid + t * 256;                       // 1250 groups total
        if (i < NCLASS / 8) kv[t] = *(const uint4*)(srow + i * 8);
    }
    __syncthreads();                                 // zeroed LDS visible

    // packed histogram: branchless, one u32 atomic per key
    #pragma unroll
    for (int t = 0; t < 5; ++t) {
        int i = tid + t * 256;
        if (i < NCLASS / 8) {
            unsigned int p[4] = {kv[t].x, kv[t].y, kv[t].z, kv[t].w};
            #pragma unroll
            for (int q = 0; q < 4; ++q) {
                unsigned int klo = p[q] & 0xFFFFu;
                unsigned int khi = p[q] >> 16;
                atomicAdd(&hist[klo >> 5], 0x100000u | (klo & 31u));
                atomicAdd(&hist[khi >> 5], 0x100000u | (khi & 31u));
            }
        }
    }
    __syncthreads();
    if (tid == 0) {
        s_pos = key16val(poskey);
        // exclude positive: dec count and its r contribution
        hist[poskey >> 5] -= 0x100000u | ((unsigned int)poskey & 31u);
    }
    __syncthreads();

    // ---- suffix scan over 2048 bins (counts); packed words kept live ----
    uint4 h0 = *(const uint4*)&hist[tid * 8];
    uint4 h1 = *(const uint4*)&hist[tid * 8 + 4];
    unsigned int wd[8] = {h0.x, h0.y, h0.z, h0.w, h1.x, h1.y, h1.z, h1.w};
    unsigned int sfx[8];
    sfx[7] = wd[7] >> 20;
    #pragma unroll
    for (int i = 6; i >= 0; --i) sfx[i] = sfx[i + 1] + (wd[i] >> 20);
    psum[tid] = sfx[0];
    __syncthreads();
    if (w == 0) {
        uint4 g = *(const uint4*)&psum[lane * 4];
        unsigned int gs = g.x + g.y + g.z + g.w;
        unsigned int s = gs;
        #pragma unroll
        for (int off = 1; off < 64; off <<= 1) {
            unsigned int o = __shfl_down(s, off);
            if (lane + off < 64) s += o;
        }
        unsigned int above = s - gs;       // partials in strictly-higher lanes
        unsigned int a3 = above;
        unsigned int a2 = a3 + g.w;
        unsigned int a1 = a2 + g.z;
        unsigned int a0 = a1 + g.y;
        psum[lane * 4 + 0] = a0; psum[lane * 4 + 1] = a1;
        psum[lane * 4 + 2] = a2; psum[lane * 4 + 3] = a3;
    }
    __syncthreads();
    {
        unsigned int add = psum[tid];      // keys in bins of threads > tid
        #pragma unroll
        for (int i = 0; i < 8; ++i) {
            unsigned int cur = sfx[i] + add;
            unsigned int nxt = ((i < 7) ? sfx[i + 1] : 0u) + add;
            if (cur >= KSEL && nxt < KSEL) {   // exactly one (tid,i) matches
                s_b    = (unsigned int)(tid * 8 + i);
                s_fill = KSEL - nxt;
                s_cntb = sfx[i] - ((i < 7) ? sfx[i + 1] : 0u);
            }
        }
    }
    __syncthreads();

    // ---- denominator ----
    const unsigned int b = s_b;
    float sum = 0.f, bsum = 0.f;           // bsum used by exact fallback only
    if (b >= 1024u) {
        // fast path: per-bin mean exp from packed words
        const float fillf = (float)s_fill;
        #pragma unroll
        for (int i = 0; i < 8; ++i) {
            unsigned int bin = (unsigned int)(tid * 8 + i);
            unsigned int c = wd[i] >> 20;
            if (bin >= b && c) {
                float rbar = (float)(wd[i] & 0xFFFFFu) / (float)c;
                unsigned int kb = bin << 5;
                float v0  = key16val(kb);
                float v32 = key16val(kb + 32u);
                float vm  = v0 + (v32 - v0) * (rbar * 0.03125f);
                float e = __expf(vm - MLOG);
                sum += ((bin > b) ? (float)c : fillf) * e;
            }
        }
    } else {
        // exact fallback: re-read keys (L3-hot), old two-class exp sum
        for (int i = tid; i < NCLASS / 8; i += 256) {
            uint4 pk = *(const uint4*)(srow + i * 8);
            unsigned int p[4] = {pk.x, pk.y, pk.z, pk.w};
            #pragma unroll
            for (int q = 0; q < 4; ++q) {
                unsigned int klo = p[q] & 0xFFFFu;
                unsigned int khi = p[q] >> 16;
                unsigned int blo = klo >> 5, bhi = khi >> 5;
                int idx = i * 8 + q * 2;
                if (blo >= b && idx != label) {
                    float e = __expf(key16val(klo) - MLOG);
                    if (blo > b) sum += e; else bsum += e;
                }
                if (bhi >= b && (idx + 1) != label) {
                    float e = __expf(key16val(khi) - MLOG);
                    if (bhi > b) sum += e; else bsum += e;
                }
            }
        }
    }
    #pragma unroll
    for (int off = 32; off; off >>= 1) {
        sum  += __shfl_xor(sum, off);
        bsum += __shfl_xor(bsum, off);
    }
    if (lane == 0) { fred[w] = sum; fred[4 + w] = bsum; }
    __syncthreads();

    if (tid == 0) {
        float S  = fred[0] + fred[1] + fred[2] + fred[3];
        float Bs = fred[4] + fred[5] + fred[6] + fred[7];   // 0 on fast path
        float ep = __expf(s_pos - MLOG);
        float denom = S + Bs * ((float)s_fill / (float)s_cntb) + ep;
        float p  = ep / denom;
        float ce = -logf(p + 1e-8f);
        float focal = 0.25f * (1.0f - p) * (1.0f - p) * ce;
        partials[row0 + rl] = focal * cw[label] * (1.0f / (float)BATCH);
    }
}

// -------------------------------------------------------------- reduce ------
// Single block: sum 4096 partials -> out[0]. No atomics anywhere.
__global__ __launch_bounds__(256) void reduce_kernel(
    const float* __restrict__ partials, float* __restrict__ out)
{
    __shared__ float red[4];
    const int tid = threadIdx.x;
    float s = 0.f;
    #pragma unroll
    for (int t = 0; t < BATCH / 256; ++t)        // 16 loads/thread
        s += partials[tid + t * 256];
    #pragma unroll
    for (int off = 32; off; off >>= 1) s += __shfl_xor(s, off);
    if ((tid & 63) == 0) red[tid >> 6] = s;
    __syncthreads();
    if (tid == 0) out[0] = red[0] + red[1] + red[2] + red[3];
}

// ------------------------------------------------------------ launcher ------
extern "C" void kernel_launch(void* const* d_in, const int* in_sizes, int n_in,
                              void* d_out, int out_size, void* d_ws, size_t ws_size,
                              hipStream_t stream) {
    const float* emb    = (const float*)d_in[0];   // 4096 x 128
    const int*   labels = (const int*)d_in[1];     // 4096
    const float* cw     = (const float*)d_in[2];   // 10000
    const float* px     = (const float*)d_in[3];   // 10000 x 128
    float* out = (float*)d_out;
    char*  wsc = (char*)d_ws;

    unsigned short* px_bf  = (unsigned short*)wsc;               // 10000*128 bf16
    unsigned short* emb_bf = (unsigned short*)(wsc + 2560000);   // 4096*128 bf16
    float*          parts  = (float*)(wsc + 3608576);            // 4096 f32
    unsigned short* simk   = (unsigned short*)(wsc + 3624960);   // chunk x 10000 key16

    size_t fixed = 3624960;
    size_t avail = (ws_size > fixed) ? (ws_size - fixed) : 0;
    long long cap = (long long)(avail / ((size_t)NCLASS * 2));
    int chunk = (int)((cap / 128) * 128);
    if (chunk > BATCH) chunk = BATCH;
    if (chunk < 128) chunk = 128;

    prep_kernel<<<3524, 256, 0, stream>>>(emb, px, px_bf, emb_bf);

    for (int r0 = 0; r0 < BATCH; r0 += chunk) {
        int rows = (BATCH - r0 < chunk) ? (BATCH - r0) : chunk;
        dim3 ggrid((NCLASS + 127) / 128, rows / 128);
        gemm_kernel<<<ggrid, 256, 0, stream>>>(emb_bf, px_bf, simk, r0);
        select_kernel<<<rows, 256, 0, stream>>>(simk, labels, cw, parts, r0);
    }
    reduce_kernel<<<1, 256, 0, stream>>>(parts, out);
}

// Round 6
// 124.818 us; speedup vs baseline: 1.8732x; 1.0468x over previous
//
#include <hip/hip_runtime.h>
#include <hip/hip_bf16.h>
#include <hip/hip_fp16.h>

// EnhancedProxyNCALoss: B=4096, C=10000, D=128, SCALE=10, alpha=.25, gamma=2,
// k = int(9999*0.3) = 2999.
// Pipeline: prep (normalize+bf16 into ws) ->
//           bf16 MFMA gemm writing sim as 16-bit monotonic half-keys ->
//           per-row single-pass packed-histogram select -> 1-block reduce.
// R6: (a) gemm XCD-locality swizzle: 1-D grid, xcd = L&7 owns a 4-row-tile
//     band, walks col tiles col-major within the band -> B-tile reuse
//     distance 79 blocks -> 4 blocks, kills the 41 MB HBM over-fetch
//     (unique inputs are 3.6 MB). (b) select: hist-zero barrier hoisted
//     BEFORE the row loads so LDS atomics overlap load arrival (counted
//     vmcnt instead of pre-barrier vmcnt(0) drain).

#define BATCH   4096
#define NCLASS  10000
#define EDIM    128
#define KSEL    2999
#define LDK     136
#define MLOG    10.0f   // sim <= 10 always (cosine * SCALE) -> safe softmax max

typedef __attribute__((ext_vector_type(8))) short short8;
typedef __attribute__((ext_vector_type(4))) float floatx4;

__device__ __forceinline__ unsigned short f2bf(float f) {
    unsigned int u = __float_as_uint(f);
    unsigned int r = (u + 0x7FFFu + ((u >> 16) & 1u)) >> 16;   // RNE
    return (unsigned short)r;
}
// float -> half (RNE) -> monotonic 16-bit key (order-preserving)
__device__ __forceinline__ unsigned int f2key16(float x) {
    unsigned short hb = __half_as_ushort(__float2half(x));
    return (hb & 0x8000u) ? (unsigned int)(~hb & 0xFFFFu)
                          : (unsigned int)(hb | 0x8000u);
}
__device__ __forceinline__ float key16val(unsigned int k) {
    unsigned short hb = (k & 0x8000u) ? (unsigned short)(k ^ 0x8000u)
                                      : (unsigned short)(~k & 0xFFFFu);
    return __half2float(__ushort_as_half(hb));
}

// ---------------------------------------------------------------- prep ------
__global__ __launch_bounds__(256) void prep_kernel(
    const float* __restrict__ emb, const float* __restrict__ px,
    unsigned short* __restrict__ px_bf, unsigned short* __restrict__ emb_bf)
{
    const int tid  = threadIdx.x;
    const int lane = tid & 63;
    const int w    = tid >> 6;
    const int row  = blockIdx.x * 4 + w;   // grid = 3524 -> rows 0..14095

    const float* src;
    unsigned short* dst;
    float scale;
    if (row < NCLASS) {
        src = px + (size_t)row * EDIM;  dst = px_bf + (size_t)row * EDIM;  scale = 1.0f;
    } else {
        int r = row - NCLASS;
        src = emb + (size_t)r * EDIM;   dst = emb_bf + (size_t)r * EDIM;   scale = 10.0f;
    }
    float a = src[lane], b = src[lane + 64];
    float ss = a * a + b * b;
    #pragma unroll
    for (int off = 32; off; off >>= 1) ss += __shfl_xor(ss, off);
    float inv = scale / fmaxf(sqrtf(ss), 1e-12f);
    dst[lane]      = f2bf(a * inv);
    dst[lane + 64] = f2bf(b * inv);
}

// ---------------------------------------------------------------- gemm ------
// sim = emb10_hat . px_hat^T, bf16 MFMA 16x16x32, fp32 acc, 128x128 tile.
// 1-D grid with XCD-locality mapping (see R6 header). Epilogue: fp32 ->
// half -> monotonic key16, LDS transpose (reuse Als), coalesced uint4 stores.
__global__ __launch_bounds__(256) void gemm_kernel(
    const unsigned short* __restrict__ emb_bf,
    const unsigned short* __restrict__ px_bf,
    unsigned short* __restrict__ simk, int row0, int nby)
{
    __shared__ __align__(16) unsigned short Als[128 * LDK];
    __shared__ __align__(16) unsigned short Bls[128 * LDK];

    const int NBX = (NCLASS + 127) / 128;   // 79 col tiles
    const int tid  = threadIdx.x;
    const int lane = tid & 63;
    const int w    = tid >> 6;

    // tile mapping: per-XCD row band, col-major walk inside the band
    int ct, rt;
    {
        int L = blockIdx.x;
        if ((nby & 7) == 0) {
            int rpx = nby >> 3;            // row tiles per XCD
            int xcd = L & 7;
            int s   = L >> 3;
            rt = xcd * rpx + (s % rpx);
            ct = s / rpx;
        } else {
            ct = L % NBX; rt = L / NBX;
        }
    }
    const int c0   = ct * 128;
    const int rg0  = row0 + rt * 128;

    #pragma unroll
    for (int i = 0; i < 8; ++i) {
        int c  = tid + i * 256;
        int r  = c >> 4;
        int kc = (c & 15) << 3;
        uint4 v = *(const uint4*)(emb_bf + (size_t)(rg0 + r) * EDIM + kc);
        *(uint4*)(Als + r * LDK + kc) = v;
    }
    #pragma unroll
    for (int i = 0; i < 8; ++i) {
        int c  = tid + i * 256;
        int n  = c >> 4;
        int kc = (c & 15) << 3;
        uint4 v = make_uint4(0u, 0u, 0u, 0u);
        if (c0 + n < NCLASS)
            v = *(const uint4*)(px_bf + (size_t)(c0 + n) * EDIM + kc);
        *(uint4*)(Bls + n * LDK + kc) = v;
    }
    __syncthreads();

    const int wr = (w >> 1) * 64;
    const int wc = (w & 1) * 64;
    const int fm = lane & 15;
    const int fq = lane >> 4;

    floatx4 acc[4][4];
    #pragma unroll
    for (int i = 0; i < 4; ++i)
        #pragma unroll
        for (int j = 0; j < 4; ++j)
            acc[i][j] = (floatx4){0.f, 0.f, 0.f, 0.f};

    #pragma unroll
    for (int kk = 0; kk < 4; ++kk) {
        const int kof = kk * 32 + fq * 8;
        short8 a[4], b[4];
        #pragma unroll
        for (int i = 0; i < 4; ++i)
            a[i] = *(const short8*)(Als + (wr + i * 16 + fm) * LDK + kof);
        #pragma unroll
        for (int j = 0; j < 4; ++j)
            b[j] = *(const short8*)(Bls + (wc + j * 16 + fm) * LDK + kof);
        #pragma unroll
        for (int i = 0; i < 4; ++i)
            #pragma unroll
            for (int j = 0; j < 4; ++j)
                acc[i][j] = __builtin_amdgcn_mfma_f32_16x16x32_bf16(
                    a[i], b[j], acc[i][j], 0, 0, 0);
    }

    __syncthreads();                       // all LDS reads done; reuse Als
    unsigned short* T = Als;               // 128 x LDK key16 tile
    // C/D layout: col = lane&15, row = (lane>>4)*4 + reg
    #pragma unroll
    for (int j = 0; j < 4; ++j) {
        int col = wc + j * 16 + fm;
        #pragma unroll
        for (int i = 0; i < 4; ++i) {
            int rbase = wr + i * 16 + fq * 4;
            #pragma unroll
            for (int r = 0; r < 4; ++r)
                T[(rbase + r) * LDK + col] = (unsigned short)f2key16(acc[i][j][r]);
        }
    }
    __syncthreads();

    const int rl0 = rt * 128;
    #pragma unroll
    for (int t = 0; t < 8; ++t) {
        int idx = t * 256 + tid;
        int rowl = idx >> 4;
        int g    = idx & 15;
        int col  = c0 + g * 8;
        if (col < NCLASS) {                // 10000 % 8 == 0 -> group all-valid
            uint4 v = *(const uint4*)(T + rowl * LDK + g * 8);
            *(uint4*)(simk + (size_t)(rl0 + rowl) * NCLASS + col) = v;
        }
    }
}

// -------------------------------------------------------------- select ------
// One block per batch row, SINGLE pass over the 10000 keys. Packed histogram:
//   hist[bin] += (1<<20) | (key & 31)     (one ds_add_u32 per key)
// count = hist>>20, r-sum = hist & 0xFFFFF. Register suffix-scan on counts
// finds boundary bin b (KSEL-th largest). Fast path (b >= 1024, i.e. positive
// threshold -- always true here): denominator from bins,
//   sum_{bin>b} cnt*exp(vmean-MLOG) + fill*exp(vmean_b-MLOG),
// vmean = v0 + (rbar/32)*(v32-v0)  (exact: value affine in key bits per bin).
// Exact fallback (re-read keys from global, L3-hot) if b < 1024.
// Result: PLAIN STORE to partials[row] (no global atomic).
__global__ __launch_bounds__(256, 8) void select_kernel(
    const unsigned short* __restrict__ simk, const int* __restrict__ labels,
    const float* __restrict__ cw, float* __restrict__ partials, int row0)
{
    __shared__ __align__(16) unsigned int hist[2048];     // 8 KB (packed)
    __shared__ __align__(16) unsigned int psum[256];      // 1 KB
    __shared__ float fred[8];
    __shared__ float s_pos;
    __shared__ unsigned int s_b, s_fill, s_cntb;

    const int tid   = threadIdx.x;
    const int lane  = tid & 63;
    const int w     = tid >> 6;
    const int rl    = blockIdx.x;
    const int label = labels[row0 + rl];
    const unsigned short* srow = simk + (size_t)rl * NCLASS;

    // prefetch positive key early (consumed after hist barrier)
    unsigned short poskey = 0;
    if (tid == 0) poskey = srow[label];

    {
        uint4 z = make_uint4(0u, 0u, 0u, 0u);
        *(uint4*)&hist[tid * 8]     = z;
        *(uint4*)&hist[tid * 8 + 4] = z;
    }
    __syncthreads();            // hist zeros visible BEFORE loads issue ->
                                // atomics below overlap load arrival
    uint4 kv[5];
    kv[4] = make_uint4(0u, 0u, 0u, 0u);
    #pragma unroll
    for (int t = 0; t < 5; ++t) {
        int i = tid + t * 256;                       // 1250 groups total
        if (i < NCLASS / 8) kv[t] = *(const uint4*)(srow + i * 8);
    }

    // packed histogram: branchless, one u32 atomic per key
    #pragma unroll
    for (int t = 0; t < 5; ++t) {
        int i = tid + t * 256;
        if (i < NCLASS / 8) {
            unsigned int p[4] = {kv[t].x, kv[t].y, kv[t].z, kv[t].w};
            #pragma unroll
            for (int q = 0; q < 4; ++q) {
                unsigned int klo = p[q] & 0xFFFFu;
                unsigned int khi = p[q] >> 16;
                atomicAdd(&hist[klo >> 5], 0x100000u | (klo & 31u));
                atomicAdd(&hist[khi >> 5], 0x100000u | (khi & 31u));
            }
        }
    }
    __syncthreads();
    if (tid == 0) {
        s_pos = key16val(poskey);
        // exclude positive: dec count and its r contribution
        hist[poskey >> 5] -= 0x100000u | ((unsigned int)poskey & 31u);
    }
    __syncthreads();

    // ---- suffix scan over 2048 bins (counts); packed words kept live ----
    uint4 h0 = *(const uint4*)&hist[tid * 8];
    uint4 h1 = *(const uint4*)&hist[tid * 8 + 4];
    unsigned int wd[8] = {h0.x, h0.y, h0.z, h0.w, h1.x, h1.y, h1.z, h1.w};
    unsigned int sfx[8];
    sfx[7] = wd[7] >> 20;
    #pragma unroll
    for (int i = 6; i >= 0; --i) sfx[i] = sfx[i + 1] + (wd[i] >> 20);
    psum[tid] = sfx[0];
    __syncthreads();
    if (w == 0) {
        uint4 g = *(const uint4*)&psum[lane * 4];
        unsigned int gs = g.x + g.y + g.z + g.w;
        unsigned int s = gs;
        #pragma unroll
        for (int off = 1; off < 64; off <<= 1) {
            unsigned int o = __shfl_down(s, off);
            if (lane + off < 64) s += o;
        }
        unsigned int above = s - gs;       // partials in strictly-higher lanes
        unsigned int a3 = above;
        unsigned int a2 = a3 + g.w;
        unsigned int a1 = a2 + g.z;
        unsigned int a0 = a1 + g.y;
        psum[lane * 4 + 0] = a0; psum[lane * 4 + 1] = a1;
        psum[lane * 4 + 2] = a2; psum[lane * 4 + 3] = a3;
    }
    __syncthreads();
    {
        unsigned int add = psum[tid];      // keys in bins of threads > tid
        #pragma unroll
        for (int i = 0; i < 8; ++i) {
            unsigned int cur = sfx[i] + add;
            unsigned int nxt = ((i < 7) ? sfx[i + 1] : 0u) + add;
            if (cur >= KSEL && nxt < KSEL) {   // exactly one (tid,i) matches
                s_b    = (unsigned int)(tid * 8 + i);
                s_fill = KSEL - nxt;
                s_cntb = sfx[i] - ((i < 7) ? sfx[i + 1] : 0u);
            }
        }
    }
    __syncthreads();

    // ---- denominator ----
    const unsigned int b = s_b;
    float sum = 0.f, bsum = 0.f;           // bsum used by exact fallback only
    if (b >= 1024u) {
        // fast path: per-bin mean exp from packed words
        const float fillf = (float)s_fill;
        #pragma unroll
        for (int i = 0; i < 8; ++i) {
            unsigned int bin = (unsigned int)(tid * 8 + i);
            unsigned int c = wd[i] >> 20;
            if (bin >= b && c) {
                float rbar = (float)(wd[i] & 0xFFFFFu) / (float)c;
                unsigned int kb = bin << 5;
                float v0  = key16val(kb);
                float v32 = key16val(kb + 32u);
                float vm  = v0 + (v32 - v0) * (rbar * 0.03125f);
                float e = __expf(vm - MLOG);
                sum += ((bin > b) ? (float)c : fillf) * e;
            }
        }
    } else {
        // exact fallback: re-read keys (L3-hot), old two-class exp sum
        for (int i = tid; i < NCLASS / 8; i += 256) {
            uint4 pk = *(const uint4*)(srow + i * 8);
            unsigned int p[4] = {pk.x, pk.y, pk.z, pk.w};
            #pragma unroll
            for (int q = 0; q < 4; ++q) {
                unsigned int klo = p[q] & 0xFFFFu;
                unsigned int khi = p[q] >> 16;
                unsigned int blo = klo >> 5, bhi = khi >> 5;
                int idx = i * 8 + q * 2;
                if (blo >= b && idx != label) {
                    float e = __expf(key16val(klo) - MLOG);
                    if (blo > b) sum += e; else bsum += e;
                }
                if (bhi >= b && (idx + 1) != label) {
                    float e = __expf(key16val(khi) - MLOG);
                    if (bhi > b) sum += e; else bsum += e;
                }
            }
        }
    }
    #pragma unroll
    for (int off = 32; off; off >>= 1) {
        sum  += __shfl_xor(sum, off);
        bsum += __shfl_xor(bsum, off);
    }
    if (lane == 0) { fred[w] = sum; fred[4 + w] = bsum; }
    __syncthreads();

    if (tid == 0) {
        float S  = fred[0] + fred[1] + fred[2] + fred[3];
        float Bs = fred[4] + fred[5] + fred[6] + fred[7];   // 0 on fast path
        float ep = __expf(s_pos - MLOG);
        float denom = S + Bs * ((float)s_fill / (float)s_cntb) + ep;
        float p  = ep / denom;
        float ce = -logf(p + 1e-8f);
        float focal = 0.25f * (1.0f - p) * (1.0f - p) * ce;
        partials[row0 + rl] = focal * cw[label] * (1.0f / (float)BATCH);
    }
}

// -------------------------------------------------------------- reduce ------
// Single block: sum 4096 partials -> out[0]. No atomics anywhere.
__global__ __launch_bounds__(256) void reduce_kernel(
    const float* __restrict__ partials, float* __restrict__ out)
{
    __shared__ float red[4];
    const int tid = threadIdx.x;
    float s = 0.f;
    #pragma unroll
    for (int t = 0; t < BATCH / 256; ++t)        // 16 loads/thread
        s += partials[tid + t * 256];
    #pragma unroll
    for (int off = 32; off; off >>= 1) s += __shfl_xor(s, off);
    if ((tid & 63) == 0) red[tid >> 6] = s;
    __syncthreads();
    if (tid == 0) out[0] = red[0] + red[1] + red[2] + red[3];
}

// ------------------------------------------------------------ launcher ------
extern "C" void kernel_launch(void* const* d_in, const int* in_sizes, int n_in,
                              void* d_out, int out_size, void* d_ws, size_t ws_size,
                              hipStream_t stream) {
    const float* emb    = (const float*)d_in[0];   // 4096 x 128
    const int*   labels = (const int*)d_in[1];     // 4096
    const float* cw     = (const float*)d_in[2];   // 10000
    const float* px     = (const float*)d_in[3];   // 10000 x 128
    float* out = (float*)d_out;
    char*  wsc = (char*)d_ws;

    unsigned short* px_bf  = (unsigned short*)wsc;               // 10000*128 bf16
    unsigned short* emb_bf = (unsigned short*)(wsc + 2560000);   // 4096*128 bf16
    float*          parts  = (float*)(wsc + 3608576);            // 4096 f32
    unsigned short* simk   = (unsigned short*)(wsc + 3624960);   // chunk x 10000 key16

    size_t fixed = 3624960;
    size_t avail = (ws_size > fixed) ? (ws_size - fixed) : 0;
    long long cap = (long long)(avail / ((size_t)NCLASS * 2));
    int chunk = (int)((cap / 128) * 128);
    if (chunk > BATCH) chunk = BATCH;
    if (chunk < 128) chunk = 128;

    prep_kernel<<<3524, 256, 0, stream>>>(emb, px, px_bf, emb_bf);

    const int NBX = (NCLASS + 127) / 128;   // 79
    for (int r0 = 0; r0 < BATCH; r0 += chunk) {
        int rows = (BATCH - r0 < chunk) ? (BATCH - r0) : chunk;
        int nby  = rows / 128;
        gemm_kernel<<<NBX * nby, 256, 0, stream>>>(emb_bf, px_bf, simk, r0, nby);
        select_kernel<<<rows, 256, 0, stream>>>(simk, labels, cw, parts, r0);
    }
    reduce_kernel<<<1, 256, 0, stream>>>(parts, out);
}